// Round 1
// baseline (1972.627 us; speedup 1.0000x reference)
//
#include <hip/hip_runtime.h>
#include <math.h>

#define NN 4096

// ---------- block reduction helpers (blockDim.x == 256 assumed) ----------

__device__ __forceinline__ double blockSumD(double v) {
  __shared__ double w[4];
  #pragma unroll
  for (int o = 32; o > 0; o >>= 1) v += __shfl_down(v, o, 64);
  __syncthreads();
  if ((threadIdx.x & 63) == 0) w[threadIdx.x >> 6] = v;
  __syncthreads();
  return w[0] + w[1] + w[2] + w[3];
}

__device__ __forceinline__ float blockMaxF(float v) {
  __shared__ float w[4];
  #pragma unroll
  for (int o = 32; o > 0; o >>= 1) v = fmaxf(v, __shfl_down(v, o, 64));
  __syncthreads();
  if ((threadIdx.x & 63) == 0) w[threadIdx.x >> 6] = v;
  __syncthreads();
  return fmaxf(fmaxf(w[0], w[1]), fmaxf(w[2], w[3]));
}

// ---------- kernel 1: row softmax of x and y, plus row sum-of-squares ----------
// grid = 2*NN blocks; block r<NN handles x row r -> sx, else y row (r-NN) -> sy.
// rowsq[0..NN-1] = x2, rowsq[NN..2NN-1] = y2.

__global__ void softmax_rows(const float* __restrict__ x, const float* __restrict__ y,
                             float* __restrict__ sx, float* __restrict__ sy,
                             float* __restrict__ rowsq) {
  int row = blockIdx.x;
  int r = (row < NN) ? row : row - NN;
  const float* __restrict__ src = (row < NN) ? x : y;
  float* __restrict__ dst = (row < NN) ? sx : sy;
  size_t base = (size_t)r * NN;
  int t = threadIdx.x;

  float v[16];
  float m = -3.402823466e38f;
  #pragma unroll
  for (int j = 0; j < 16; ++j) {
    v[j] = src[base + t + 256 * j];
    m = fmaxf(m, v[j]);
  }
  float M = blockMaxF(m);

  double s = 0.0;
  #pragma unroll
  for (int j = 0; j < 16; ++j) {
    v[j] = expf(v[j] - M);
    s += (double)v[j];
  }
  double S = blockSumD(s);
  double inv = 1.0 / S;

  double q = 0.0;
  #pragma unroll
  for (int j = 0; j < 16; ++j) {
    float p = (float)((double)v[j] * inv);
    dst[base + t + 256 * j] = p;
    q += (double)p * (double)p;
  }
  double Q = blockSumD(q);
  if (t == 0) rowsq[row] = (float)Q;
}

// ---------- kernel 2: C[i,j] = x2[i] + y2[j] - 2 * sum_k sx[i,k]*sy[j,k] ----------
// NT fp32 GEMM, 128x128 tile, BK=32, 256 threads, 8x8 microtile per thread.

__global__ __launch_bounds__(256) void gemm_nt(
    const float* __restrict__ A,      // sx (note: may be 4B-misaligned base)
    const float* __restrict__ B,      // sy
    const float* __restrict__ rowsq,  // x2 | y2
    float* __restrict__ C) {
  __shared__ float As[32 * 132];  // [kk][m], stride 132 (pad keeps 16B align + banks)
  __shared__ float Bs[32 * 132];  // [kk][n]
  int t = threadIdx.x;
  int i0 = blockIdx.y * 128;
  int j0 = blockIdx.x * 128;
  int tx = t & 15, ty = t >> 4;   // 16x16 thread grid
  int kk0 = t & 31, rw0 = t >> 5; // staging: lane -> k-offset, row group
  float acc[8][8] = {{0.0f}};

  for (int kc = 0; kc < NN; kc += 32) {
    float a[16], b[16];
    #pragma unroll
    for (int p = 0; p < 16; ++p) {
      int row = rw0 + 8 * p;
      a[p] = A[(size_t)(i0 + row) * NN + kc + kk0];
      b[p] = B[(size_t)(j0 + row) * NN + kc + kk0];
    }
    __syncthreads();
    #pragma unroll
    for (int p = 0; p < 16; ++p) {
      int row = rw0 + 8 * p;
      As[kk0 * 132 + row] = a[p];
      Bs[kk0 * 132 + row] = b[p];
    }
    __syncthreads();
    #pragma unroll 8
    for (int kk = 0; kk < 32; ++kk) {
      const float4 a0 = *(const float4*)(As + kk * 132 + ty * 8);
      const float4 a1 = *(const float4*)(As + kk * 132 + ty * 8 + 4);
      const float4 b0 = *(const float4*)(Bs + kk * 132 + tx * 8);
      const float4 b1 = *(const float4*)(Bs + kk * 132 + tx * 8 + 4);
      float av[8] = {a0.x, a0.y, a0.z, a0.w, a1.x, a1.y, a1.z, a1.w};
      float bv[8] = {b0.x, b0.y, b0.z, b0.w, b1.x, b1.y, b1.z, b1.w};
      #pragma unroll
      for (int r = 0; r < 8; ++r)
        #pragma unroll
        for (int c = 0; c < 8; ++c)
          acc[r][c] = fmaf(av[r], bv[c], acc[r][c]);
    }
  }

  float x2v[8], y2v[8];
  #pragma unroll
  for (int r = 0; r < 8; ++r) x2v[r] = rowsq[i0 + ty * 8 + r];
  #pragma unroll
  for (int c = 0; c < 8; ++c) y2v[c] = rowsq[NN + j0 + tx * 8 + c];
  #pragma unroll
  for (int r = 0; r < 8; ++r) {
    size_t off = (size_t)(i0 + ty * 8 + r) * NN + j0 + tx * 8;
    #pragma unroll
    for (int c = 0; c < 8; ++c)
      C[off + c] = x2v[r] + y2v[c] - 2.0f * acc[r][c];
  }
}

// ---------- kernel 3: partial column sums of exp(-C/EPS) ----------
// grid (16, 32): blockIdx.x -> 256-col group, blockIdx.y -> 128-row chunk.

__global__ void col_lse_partial(const float* __restrict__ C, double* __restrict__ part) {
  int col = blockIdx.x * 256 + threadIdx.x;
  int r0 = blockIdx.y * 128;
  double s = 0.0;
  for (int r = 0; r < 128; ++r) {
    float c = C[(size_t)(r0 + r) * NN + col];
    s += exp(((double)(-c)) / 0.1);
  }
  part[(size_t)blockIdx.y * NN + col] = s;
}

// ---------- kernel 4: finalize L_j, store s_j = log_nu - L_j (double) ----------

__global__ void col_lse_final(const double* __restrict__ part, double* __restrict__ sd) {
  int col = blockIdx.x * 256 + threadIdx.x;
  double s = 0.0;
  #pragma unroll
  for (int ch = 0; ch < 32; ++ch) s += part[(size_t)ch * NN + col];
  double log_nu = log(1.0 / (double)NN + 1e-8);
  sd[col] = log_nu - log(s);
}

// ---------- kernel 5: pi = exp(-C/EPS + s_j), cost partials ----------
// grid 8192 blocks x 256 thr, 8 elements/thread (strided, coalesced).

__global__ void pi_cost(const float* __restrict__ Cm, const double* __restrict__ sd,
                        float* __restrict__ pi, double* __restrict__ costpart) {
  size_t idx0 = (size_t)blockIdx.x * 2048 + threadIdx.x;
  double acc = 0.0;
  #pragma unroll
  for (int j = 0; j < 8; ++j) {
    size_t idx = idx0 + 256 * j;
    float c = Cm[idx];
    int col = (int)(idx & (NN - 1));
    double m = ((double)(-c)) / 0.1 + sd[col];
    double p = exp(m);
    pi[idx] = (float)p;
    acc += p * (double)c;
  }
  double total = blockSumD(acc);
  if (threadIdx.x == 0) costpart[blockIdx.x] = total;
}

// ---------- kernel 6: final cost reduction ----------

__global__ void cost_final(const double* __restrict__ costpart, float* __restrict__ out) {
  double s = 0.0;
  #pragma unroll
  for (int j = 0; j < 32; ++j) s += costpart[threadIdx.x + 256 * j];
  double total = blockSumD(s);
  if (threadIdx.x == 0) out[0] = (float)total;
}

// ---------- launch ----------

extern "C" void kernel_launch(void* const* d_in, const int* in_sizes, int n_in,
                              void* d_out, int out_size, void* d_ws, size_t ws_size,
                              hipStream_t stream) {
  const float* x = (const float*)d_in[0];
  const float* y = (const float*)d_in[1];
  float* out = (float*)d_out;
  float* pi = out + 1;                         // [NN*NN]
  float* Cm = out + 1 + (size_t)NN * NN;       // [NN*NN]

  char* ws = (char*)d_ws;
  float* sy = (float*)ws;                                       // NN*NN*4 = 64 MiB
  size_t off = (size_t)NN * NN * 4;
  float* rowsq = (float*)(ws + off);          off += 2 * NN * 4;   // 32 KiB
  double* sd = (double*)(ws + off);           off += NN * 8;       // 32 KiB
  double* colpart = (double*)(ws + off);      off += 32 * NN * 8;  // 1 MiB
  double* costpart = (double*)(ws + off);     off += 8192 * 8;     // 64 KiB

  float* sx = pi;  // park softmax(x) in the pi output region; overwritten by pi later

  hipLaunchKernelGGL(softmax_rows, dim3(2 * NN), dim3(256), 0, stream, x, y, sx, sy, rowsq);
  hipLaunchKernelGGL(gemm_nt, dim3(32, 32), dim3(256), 0, stream, sx, sy, rowsq, Cm);
  hipLaunchKernelGGL(col_lse_partial, dim3(16, 32), dim3(256), 0, stream, Cm, colpart);
  hipLaunchKernelGGL(col_lse_final, dim3(16), dim3(256), 0, stream, colpart, sd);
  hipLaunchKernelGGL(pi_cost, dim3(8192), dim3(256), 0, stream, Cm, sd, pi, costpart);
  hipLaunchKernelGGL(cost_final, dim3(1), dim3(256), 0, stream, costpart, out);
}

// Round 2
// 449.251 us; speedup vs baseline: 4.3909x; 4.3909x over previous
//
#include <hip/hip_runtime.h>
#include <math.h>

#define NN 4096

typedef __bf16 bf16;
typedef __attribute__((ext_vector_type(8))) __bf16 bf16x8;
typedef __attribute__((ext_vector_type(4))) float f32x4;

__device__ __forceinline__ void gld16(const void* g, void* l) {
  __builtin_amdgcn_global_load_lds((const __attribute__((address_space(1))) void*)g,
                                   (__attribute__((address_space(3))) void*)l, 16, 0, 0);
}

// ---------- block reduction helpers (blockDim.x == 256) ----------

__device__ __forceinline__ double blockSumD(double v) {
  __shared__ double w[4];
  #pragma unroll
  for (int o = 32; o > 0; o >>= 1) v += __shfl_down(v, o, 64);
  __syncthreads();
  if ((threadIdx.x & 63) == 0) w[threadIdx.x >> 6] = v;
  __syncthreads();
  return w[0] + w[1] + w[2] + w[3];
}

__device__ __forceinline__ float blockMaxF(float v) {
  __shared__ float w[4];
  #pragma unroll
  for (int o = 32; o > 0; o >>= 1) v = fmaxf(v, __shfl_down(v, o, 64));
  __syncthreads();
  if ((threadIdx.x & 63) == 0) w[threadIdx.x >> 6] = v;
  __syncthreads();
  return fmaxf(fmaxf(w[0], w[1]), fmaxf(w[2], w[3]));
}

// ---------- kernel 1: row softmax of x,y -> bf16, plus exact row sum-of-squares ----------

__global__ void softmax_rows(const float* __restrict__ x, const float* __restrict__ y,
                             bf16* __restrict__ xh, bf16* __restrict__ yh,
                             float* __restrict__ rowsq) {
  int row = blockIdx.x;
  int r = (row < NN) ? row : row - NN;
  const float* __restrict__ src = (row < NN) ? x : y;
  bf16* __restrict__ dst = (row < NN) ? xh : yh;
  size_t base = (size_t)r * NN;
  int t = threadIdx.x;

  float v[16];
  float m = -3.402823466e38f;
  #pragma unroll
  for (int j = 0; j < 16; ++j) {
    v[j] = src[base + t + 256 * j];
    m = fmaxf(m, v[j]);
  }
  float M = blockMaxF(m);

  double s = 0.0;
  #pragma unroll
  for (int j = 0; j < 16; ++j) {
    v[j] = expf(v[j] - M);
    s += (double)v[j];
  }
  double S = blockSumD(s);
  double inv = 1.0 / S;

  double q = 0.0;
  #pragma unroll
  for (int j = 0; j < 16; ++j) {
    float p = (float)((double)v[j] * inv);
    dst[base + t + 256 * j] = (bf16)p;
    q += (double)p * (double)p;
  }
  double Q = blockSumD(q);
  if (t == 0) rowsq[row] = (float)Q;
}

// ---------- kernel 2: C = x2 + y2 - 2 * sx . sy^T   (bf16 MFMA, m97 structure) ----------
// 128x128 tile, BK=64, 4 waves, 4x4 16x16x32 MFMA tiles per wave.
// LDS layout: row-major [row][64] bf16, 16B chunks XOR-swizzled (j ^= row&7) to kill
// ds_read_b128 bank conflicts; global_load_lds width=16, dest = base + lane*16.

__global__ __launch_bounds__(256) void gemm_bt(const bf16* __restrict__ A,
                                               const bf16* __restrict__ B,
                                               const float* __restrict__ rowsq,
                                               float* __restrict__ C) {
  __shared__ __align__(16) bf16 As[128 * 64];
  __shared__ __align__(16) bf16 Bs[128 * 64];
  int t = threadIdx.x;
  int i0 = blockIdx.y * 128;
  int j0 = blockIdx.x * 128;
  int w = t >> 6, l = t & 63;
  int mrow = (w >> 1) * 64, ncol = (w & 1) * 64;
  int lr = l & 15, lq = l >> 4;

  f32x4 acc[4][4] = {};

  for (int kc = 0; kc < NN; kc += 64) {
    __syncthreads();
    #pragma unroll
    for (int q = 0; q < 4; ++q) {
      int c = t + 256 * q;              // LDS chunk index 0..1023
      int row = c >> 3;
      int jg = (c & 7) ^ (row & 7);     // swizzled source chunk within the row
      gld16(A + (size_t)(i0 + row) * NN + kc + jg * 8, (char*)As + c * 16);
    }
    #pragma unroll
    for (int q = 0; q < 4; ++q) {
      int c = t + 256 * q;
      int row = c >> 3;
      int jg = (c & 7) ^ (row & 7);
      gld16(B + (size_t)(j0 + row) * NN + kc + jg * 8, (char*)Bs + c * 16);
    }
    __syncthreads();

    #pragma unroll
    for (int s = 0; s < 2; ++s) {
      bf16x8 af[4], bg[4];
      #pragma unroll
      for (int i = 0; i < 4; ++i) {
        int ra = mrow + 16 * i + lr;
        int ja = (s * 4 + lq) ^ (ra & 7);
        af[i] = *(const bf16x8*)((const char*)As + (ra * 8 + ja) * 16);
        int rb = ncol + 16 * i + lr;
        int jb = (s * 4 + lq) ^ (rb & 7);
        bg[i] = *(const bf16x8*)((const char*)Bs + (rb * 8 + jb) * 16);
      }
      #pragma unroll
      for (int i = 0; i < 4; ++i)
        #pragma unroll
        for (int jj = 0; jj < 4; ++jj)
          acc[i][jj] = __builtin_amdgcn_mfma_f32_16x16x32_bf16(af[i], bg[jj], acc[i][jj], 0, 0, 0);
    }
  }

  float y2v[4];
  #pragma unroll
  for (int jj = 0; jj < 4; ++jj) y2v[jj] = rowsq[NN + j0 + ncol + 16 * jj + lr];
  #pragma unroll
  for (int i = 0; i < 4; ++i) {
    #pragma unroll
    for (int r = 0; r < 4; ++r) {
      int grow = i0 + mrow + 16 * i + lq * 4 + r;
      float x2 = rowsq[grow];
      size_t rowoff = (size_t)grow * NN + j0 + ncol;
      #pragma unroll
      for (int jj = 0; jj < 4; ++jj)
        C[rowoff + 16 * jj + lr] = x2 + y2v[jj] - 2.0f * acc[i][jj][r];
    }
  }
}

// ---------- kernel 3: partial column sums of exp(-C/EPS) ----------

__global__ void col_lse_partial(const float* __restrict__ C, double* __restrict__ part) {
  int col = blockIdx.x * 256 + threadIdx.x;
  int r0 = blockIdx.y * 128;
  double s = 0.0;
  for (int r = 0; r < 128; ++r) {
    float c = C[(size_t)(r0 + r) * NN + col];
    s += exp(((double)(-c)) / 0.1);
  }
  part[(size_t)blockIdx.y * NN + col] = s;
}

// ---------- kernel 4: s_j = log_nu - log(colsum) ----------

__global__ void col_lse_final(const double* __restrict__ part, double* __restrict__ sd) {
  int col = blockIdx.x * 256 + threadIdx.x;
  double s = 0.0;
  #pragma unroll
  for (int ch = 0; ch < 32; ++ch) s += part[(size_t)ch * NN + col];
  double log_nu = log(1.0 / (double)NN + 1e-8);
  sd[col] = log_nu - log(s);
}

// ---------- kernel 5: pi = exp(-C/EPS + s_j), cost partials ----------

__global__ void pi_cost(const float* __restrict__ Cm, const double* __restrict__ sd,
                        float* __restrict__ pi, double* __restrict__ costpart) {
  size_t idx0 = (size_t)blockIdx.x * 2048 + threadIdx.x;
  double acc = 0.0;
  #pragma unroll
  for (int j = 0; j < 8; ++j) {
    size_t idx = idx0 + 256 * j;
    float c = Cm[idx];
    int col = (int)(idx & (NN - 1));
    double m = ((double)(-c)) / 0.1 + sd[col];
    double p = exp(m);
    pi[idx] = (float)p;
    acc += p * (double)c;
  }
  double total = blockSumD(acc);
  if (threadIdx.x == 0) costpart[blockIdx.x] = total;
}

// ---------- kernel 6: final cost reduction ----------

__global__ void cost_final(const double* __restrict__ costpart, float* __restrict__ out) {
  double s = 0.0;
  #pragma unroll
  for (int j = 0; j < 32; ++j) s += costpart[threadIdx.x + 256 * j];
  double total = blockSumD(s);
  if (threadIdx.x == 0) out[0] = (float)total;
}

// ---------- launch ----------

extern "C" void kernel_launch(void* const* d_in, const int* in_sizes, int n_in,
                              void* d_out, int out_size, void* d_ws, size_t ws_size,
                              hipStream_t stream) {
  const float* x = (const float*)d_in[0];
  const float* y = (const float*)d_in[1];
  float* out = (float*)d_out;
  float* pi = out + 1;                          // [NN*NN] floats
  float* Cm = out + 1 + (size_t)NN * NN;        // [NN*NN] floats

  char* ws = (char*)d_ws;
  bf16* xh = (bf16*)ws;                                          // 32 MiB
  bf16* yh = xh + (size_t)NN * NN;                               // 32 MiB
  size_t off = (size_t)NN * NN * 2 * 2;
  float* rowsq = (float*)(ws + off);       off += 2 * NN * 4;    // 32 KiB
  double* sd = (double*)(ws + off);        off += NN * 8;        // 32 KiB
  double* costpart = (double*)(ws + off);  off += 8192 * 8;      // 64 KiB

  // colpart (1 MiB) parked in the tail of the pi output region; it is fully
  // consumed by col_lse_final BEFORE pi_cost overwrites the region with pi.
  double* colpart = (double*)((char*)d_out + 66060288);          // 8B-aligned, ends 4B before Cm

  hipLaunchKernelGGL(softmax_rows, dim3(2 * NN), dim3(256), 0, stream, x, y, xh, yh, rowsq);
  hipLaunchKernelGGL(gemm_bt, dim3(32, 32), dim3(256), 0, stream, xh, yh, rowsq, Cm);
  hipLaunchKernelGGL(col_lse_partial, dim3(16, 32), dim3(256), 0, stream, Cm, colpart);
  hipLaunchKernelGGL(col_lse_final, dim3(16), dim3(256), 0, stream, colpart, sd);
  hipLaunchKernelGGL(pi_cost, dim3(8192), dim3(256), 0, stream, Cm, sd, pi, costpart);
  hipLaunchKernelGGL(cost_final, dim3(1), dim3(256), 0, stream, costpart, out);
}

// Round 3
// 398.701 us; speedup vs baseline: 4.9476x; 1.1268x over previous
//
#include <hip/hip_runtime.h>
#include <math.h>

#define NN 4096

typedef __bf16 bf16;
typedef __attribute__((ext_vector_type(4))) __bf16 bf16x4;
typedef __attribute__((ext_vector_type(8))) __bf16 bf16x8;
typedef __attribute__((ext_vector_type(4))) float f32x4;

__device__ __forceinline__ void gld16(const void* g, void* l) {
  __builtin_amdgcn_global_load_lds((const __attribute__((address_space(1))) void*)g,
                                   (__attribute__((address_space(3))) void*)l, 16, 0, 0);
}

// ---------- block reduction helpers (blockDim.x == 256) ----------

__device__ __forceinline__ double blockSumD(double v) {
  __shared__ double w[4];
  #pragma unroll
  for (int o = 32; o > 0; o >>= 1) v += __shfl_down(v, o, 64);
  __syncthreads();
  if ((threadIdx.x & 63) == 0) w[threadIdx.x >> 6] = v;
  __syncthreads();
  return w[0] + w[1] + w[2] + w[3];
}

__device__ __forceinline__ float blockMaxF(float v) {
  __shared__ float w[4];
  #pragma unroll
  for (int o = 32; o > 0; o >>= 1) v = fmaxf(v, __shfl_down(v, o, 64));
  __syncthreads();
  if ((threadIdx.x & 63) == 0) w[threadIdx.x >> 6] = v;
  __syncthreads();
  return fmaxf(fmaxf(w[0], w[1]), fmaxf(w[2], w[3]));
}

// ---------- kernel 1: row softmax of x,y -> bf16 (vectorized), exact row sum-of-squares ----------

__global__ void softmax_rows(const float* __restrict__ x, const float* __restrict__ y,
                             bf16* __restrict__ xh, bf16* __restrict__ yh,
                             float* __restrict__ rowsq) {
  int row = blockIdx.x;
  int r = (row < NN) ? row : row - NN;
  const f32x4* __restrict__ src = (const f32x4*)(((row < NN) ? x : y) + (size_t)r * NN);
  bf16x4* __restrict__ dst = (bf16x4*)(((row < NN) ? xh : yh) + (size_t)r * NN);
  int t = threadIdx.x;

  f32x4 v[4];
  float m = -3.402823466e38f;
  #pragma unroll
  for (int j = 0; j < 4; ++j) {
    v[j] = src[t + 256 * j];
    m = fmaxf(fmaxf(fmaxf(m, v[j].x), fmaxf(v[j].y, v[j].z)), v[j].w);
  }
  float M = blockMaxF(m);

  float s = 0.0f;
  #pragma unroll
  for (int j = 0; j < 4; ++j) {
    v[j].x = expf(v[j].x - M); v[j].y = expf(v[j].y - M);
    v[j].z = expf(v[j].z - M); v[j].w = expf(v[j].w - M);
    s += (v[j].x + v[j].y) + (v[j].z + v[j].w);
  }
  double S = blockSumD((double)s);
  float inv = (float)(1.0 / S);

  float q = 0.0f;
  #pragma unroll
  for (int j = 0; j < 4; ++j) {
    f32x4 p = v[j] * inv;
    bf16x4 h;
    h.x = (bf16)p.x; h.y = (bf16)p.y; h.z = (bf16)p.z; h.w = (bf16)p.w;
    dst[t + 256 * j] = h;
    q += (p.x * p.x + p.y * p.y) + (p.z * p.z + p.w * p.w);
  }
  double Q = blockSumD((double)q);
  if (t == 0) rowsq[row] = (float)Q;
}

// ---------- kernel 2: C = x2 + y2 - 2 * sx . sy^T  (bf16 MFMA) + fused column exp-sums ----------
// 128x128 tile, BK=64, 4 waves, 4x4 16x16x32 MFMA tiles/wave. XOR-swizzled LDS (0 conflicts).
// Epilogue also emits colpart[by][col] = sum over the block's 128 rows of exp(-10*C).

__global__ __launch_bounds__(256) void gemm_bt(const bf16* __restrict__ A,
                                               const bf16* __restrict__ B,
                                               const float* __restrict__ rowsq,
                                               float* __restrict__ C,
                                               float* __restrict__ colpart) {
  __shared__ __align__(16) bf16 As[128 * 64];
  __shared__ __align__(16) bf16 Bs[128 * 64];
  __shared__ float lsc[2][128];
  int t = threadIdx.x;
  int i0 = blockIdx.y * 128;
  int j0 = blockIdx.x * 128;
  int w = t >> 6, l = t & 63;
  int mrow = (w >> 1) * 64, ncol = (w & 1) * 64;
  int lr = l & 15, lq = l >> 4;

  f32x4 acc[4][4] = {};

  for (int kc = 0; kc < NN; kc += 64) {
    __syncthreads();
    #pragma unroll
    for (int q = 0; q < 4; ++q) {
      int c = t + 256 * q;              // LDS chunk index 0..1023
      int row = c >> 3;
      int jg = (c & 7) ^ (row & 7);     // swizzled source chunk within the row
      gld16(A + (size_t)(i0 + row) * NN + kc + jg * 8, (char*)As + c * 16);
    }
    #pragma unroll
    for (int q = 0; q < 4; ++q) {
      int c = t + 256 * q;
      int row = c >> 3;
      int jg = (c & 7) ^ (row & 7);
      gld16(B + (size_t)(j0 + row) * NN + kc + jg * 8, (char*)Bs + c * 16);
    }
    __syncthreads();

    #pragma unroll
    for (int s = 0; s < 2; ++s) {
      bf16x8 af[4], bg[4];
      #pragma unroll
      for (int i = 0; i < 4; ++i) {
        int ra = mrow + 16 * i + lr;
        int ja = (s * 4 + lq) ^ (ra & 7);
        af[i] = *(const bf16x8*)((const char*)As + (ra * 8 + ja) * 16);
        int rb = ncol + 16 * i + lr;
        int jb = (s * 4 + lq) ^ (rb & 7);
        bg[i] = *(const bf16x8*)((const char*)Bs + (rb * 8 + jb) * 16);
      }
      #pragma unroll
      for (int i = 0; i < 4; ++i)
        #pragma unroll
        for (int jj = 0; jj < 4; ++jj)
          acc[i][jj] = __builtin_amdgcn_mfma_f32_16x16x32_bf16(af[i], bg[jj], acc[i][jj], 0, 0, 0);
    }
  }

  float y2v[4], ec[4] = {0.f, 0.f, 0.f, 0.f};
  #pragma unroll
  for (int jj = 0; jj < 4; ++jj) y2v[jj] = rowsq[NN + j0 + ncol + 16 * jj + lr];
  #pragma unroll
  for (int i = 0; i < 4; ++i) {
    #pragma unroll
    for (int r = 0; r < 4; ++r) {
      int grow = i0 + mrow + 16 * i + lq * 4 + r;
      float x2 = rowsq[grow];
      size_t rowoff = (size_t)grow * NN + j0 + ncol;
      #pragma unroll
      for (int jj = 0; jj < 4; ++jj) {
        float cv = x2 + y2v[jj] - 2.0f * acc[i][jj][r];
        C[rowoff + 16 * jj + lr] = cv;
        ec[jj] += expf(-10.0f * cv);
      }
    }
  }
  // reduce over lq (lanes lr, lr+16, lr+32, lr+48 hold the same columns)
  #pragma unroll
  for (int jj = 0; jj < 4; ++jj) {
    ec[jj] += __shfl_xor(ec[jj], 16, 64);
    ec[jj] += __shfl_xor(ec[jj], 32, 64);
  }
  if (lq == 0) {
    #pragma unroll
    for (int jj = 0; jj < 4; ++jj) lsc[w >> 1][ncol + 16 * jj + lr] = ec[jj];
  }
  __syncthreads();
  if (t < 128) colpart[(size_t)blockIdx.y * NN + j0 + t] = lsc[0][t] + lsc[1][t];
}

// ---------- kernel 3: s_j = log_nu - log(colsum) as fp32 ----------

__global__ void col_lse_final(const float* __restrict__ colpart, float* __restrict__ sdf) {
  int col = blockIdx.x * 256 + threadIdx.x;
  double s = 0.0;
  #pragma unroll
  for (int ch = 0; ch < 32; ++ch) s += (double)colpart[(size_t)ch * NN + col];
  double log_nu = log(1.0 / (double)NN + 1e-8);
  sdf[col] = (float)(log_nu - log(s));
}

// ---------- kernel 4: pi = exp(-10*C + s_j), fused cost partials (fp32 math) ----------

__global__ void pi_cost(const float* __restrict__ Cm, const float* __restrict__ sdf,
                        float* __restrict__ pi, double* __restrict__ costpart) {
  size_t idx0 = (size_t)blockIdx.x * 2048 + threadIdx.x;
  float facc = 0.0f;
  #pragma unroll
  for (int j = 0; j < 8; ++j) {
    size_t idx = idx0 + 256 * j;
    float c = Cm[idx];
    int col = (int)(idx & (NN - 1));
    float p = expf(fmaf(-10.0f, c, sdf[col]));
    pi[idx] = p;
    facc = fmaf(p, c, facc);
  }
  double total = blockSumD((double)facc);
  if (threadIdx.x == 0) costpart[blockIdx.x] = total;
}

// ---------- kernel 5: final cost reduction ----------

__global__ void cost_final(const double* __restrict__ costpart, float* __restrict__ out) {
  double s = 0.0;
  #pragma unroll
  for (int j = 0; j < 32; ++j) s += costpart[threadIdx.x + 256 * j];
  double total = blockSumD(s);
  if (threadIdx.x == 0) out[0] = (float)total;
}

// ---------- launch ----------

extern "C" void kernel_launch(void* const* d_in, const int* in_sizes, int n_in,
                              void* d_out, int out_size, void* d_ws, size_t ws_size,
                              hipStream_t stream) {
  const float* x = (const float*)d_in[0];
  const float* y = (const float*)d_in[1];
  float* out = (float*)d_out;
  float* pi = out + 1;                          // [NN*NN] floats
  float* Cm = out + 1 + (size_t)NN * NN;        // [NN*NN] floats

  char* ws = (char*)d_ws;
  bf16* xh = (bf16*)ws;                                          // 32 MiB
  bf16* yh = xh + (size_t)NN * NN;                               // 32 MiB
  size_t off = (size_t)NN * NN * 2 * 2;
  float* rowsq = (float*)(ws + off);       off += 2 * NN * 4;    // 32 KiB
  float* sdf = (float*)(ws + off);         off += NN * 4;        // 16 KiB
  float* colpart = (float*)(ws + off);     off += 32 * NN * 4;   // 512 KiB
  double* costpart = (double*)(ws + off);  off += 8192 * 8;      // 64 KiB

  hipLaunchKernelGGL(softmax_rows, dim3(2 * NN), dim3(256), 0, stream, x, y, xh, yh, rowsq);
  hipLaunchKernelGGL(gemm_bt, dim3(32, 32), dim3(256), 0, stream, xh, yh, rowsq, Cm, colpart);
  hipLaunchKernelGGL(col_lse_final, dim3(16), dim3(256), 0, stream, colpart, sdf);
  hipLaunchKernelGGL(pi_cost, dim3(8192), dim3(256), 0, stream, Cm, sdf, pi, costpart);
  hipLaunchKernelGGL(cost_final, dim3(1), dim3(256), 0, stream, costpart, out);
}